// Round 2
// baseline (2364.772 us; speedup 1.0000x reference)
//
#include <hip/hip_runtime.h>

#define N_NODES 100000
#define N_EDGES 1600000
#define N_GRAPHS 128
#define IN_CH 768
#define OUT_CH 128

__device__ __forceinline__ float bf2f(unsigned short u) {
    return __uint_as_float(((unsigned)u) << 16);
}
__device__ __forceinline__ unsigned short f2bf(float f) {
    unsigned u = __float_as_uint(f);
    u += 0x7fffu + ((u >> 16) & 1u);   // round-to-nearest-even
    return (unsigned short)(u >> 16);
}
// read input float tensor element i, dtype selected by runtime flag (wave-uniform)
__device__ __forceinline__ float load_f(const void* p, size_t i, int f32) {
    return f32 ? ((const float*)p)[i] : bf2f(((const unsigned short*)p)[i]);
}

// ---------------------------------------------------------------- dtype detect
// bf16 x ~ N(0,1): all of the first 8192 values are finite and |v| < 6.
// fp32 x read as bf16 shorts: low half-words are ~uniform bits -> huge/inf/NaN.
__global__ void k_detect(const unsigned short* __restrict__ x, int* flag) {
    __shared__ int s;
    if (threadIdx.x == 0) s = 0;
    __syncthreads();
    int bad = 0;
    for (int j = threadIdx.x; j < 8192; j += 256) {
        float v = bf2f(x[j]);
        if (!(v > -64.f && v < 64.f)) bad = 1;   // NaN fails both -> bad
    }
    if (bad) atomicOr(&s, 1);
    __syncthreads();
    if (threadIdx.x == 0) *flag = s;
}

// ---------------------------------------------------------------- init + weight canonicalization (fp32 ws copies)
__global__ void k_init(const int* __restrict__ flag, int* deg, unsigned* pooled, int* root,
                       const void* Wc, const void* bc, const void* W0, const void* b0,
                       const void* W1, const void* b1, const void* W2, const void* b2,
                       float* fWc, float* fbc, float* fW0, float* fb0,
                       float* fW1, float* fb1, float* fW2, float* fb2) {
    int f32 = *flag;
    int i = blockIdx.x * blockDim.x + threadIdx.x;
    if (i < N_NODES) deg[i] = 0;
    if (i < N_GRAPHS * OUT_CH) pooled[i] = 0u;
    if (i < N_GRAPHS) root[i] = 0;
    if (i < IN_CH * OUT_CH) { fWc[i] = load_f(Wc, i, f32); fW0[i] = load_f(W0, i, f32); }
    if (i < 2 * OUT_CH * OUT_CH) fW1[i] = load_f(W1, i, f32);
    if (i < OUT_CH * 2) fW2[i] = load_f(W2, i, f32);
    if (i < OUT_CH) { fbc[i] = load_f(bc, i, f32); fb0[i] = load_f(b0, i, f32); fb1[i] = load_f(b1, i, f32); }
    if (i < 2) fb2[i] = load_f(b2, i, f32);
}

// ---------------------------------------------------------------- degree count
__global__ void k_count(const int* __restrict__ src, const int* __restrict__ dst, int* deg) {
    int i = blockIdx.x * blockDim.x + threadIdx.x;
    if (i >= N_EDGES) return;
    atomicAdd(&deg[src[i]], 1);
    atomicAdd(&deg[dst[i]], 1);
}

__global__ void k_dinv(const int* __restrict__ deg, float* dinv) {
    int i = blockIdx.x * blockDim.x + threadIdx.x;
    if (i >= N_NODES) return;
    int d = deg[i]; if (d < 0) d = 0;           // guard: rsqrtf never sees negative
    dinv[i] = rsqrtf((float)(d + 1));           // +1 self-loop
}

// ---------------------------------------------------------------- exclusive scan (3 stages)
__global__ void k_scan1(const int* __restrict__ deg, int* offs, int* blockSums) {
    __shared__ int s[256];
    int tid = threadIdx.x;
    int base = blockIdx.x * 1024 + tid * 4;
    int v[4]; int t = 0;
#pragma unroll
    for (int j = 0; j < 4; j++) {
        int idx = base + j;
        v[j] = (idx < N_NODES) ? deg[idx] : 0;
        t += v[j];
    }
    s[tid] = t;
    __syncthreads();
    for (int off = 1; off < 256; off <<= 1) {
        int add = (tid >= off) ? s[tid - off] : 0;
        __syncthreads();
        s[tid] += add;
        __syncthreads();
    }
    int excl = s[tid] - t;
#pragma unroll
    for (int j = 0; j < 4; j++) {
        int idx = base + j;
        if (idx < N_NODES) offs[idx] = excl;
        excl += v[j];
    }
    if (tid == 255) blockSums[blockIdx.x] = s[255];
}

__global__ void k_scan2(const int* __restrict__ blockSums, int* blockOffs, int nb) {
    if (threadIdx.x == 0 && blockIdx.x == 0) {
        int acc = 0;
        for (int b = 0; b < nb; b++) { int t = blockSums[b]; blockOffs[b] = acc; acc += t; }
    }
}

__global__ void k_scan3(int* offs, const int* __restrict__ blockOffs, int* cursor) {
    int i = blockIdx.x * blockDim.x + threadIdx.x;
    if (i >= N_NODES) return;
    int o = offs[i] + blockOffs[i >> 10];
    offs[i] = o;
    cursor[i] = o;
}

// ---------------------------------------------------------------- CSR fill
__global__ void k_fill(const int* __restrict__ src, const int* __restrict__ dst,
                       int* cursor, int* adj) {
    int i = blockIdx.x * blockDim.x + threadIdx.x;
    if (i >= N_EDGES) return;
    int s = src[i], d = dst[i];
    adj[atomicAdd(&cursor[d], 1)] = s;
    adj[atomicAdd(&cursor[s], 1)] = d;
}

// ---------------------------------------------------------------- GEMM h = x @ W_conv (simple, fp32 accum)
#define GN 4
__global__ __launch_bounds__(512) void k_gemm(const int* __restrict__ flag,
                                              const void* __restrict__ x,
                                              const float* __restrict__ W,
                                              unsigned short* __restrict__ h) {
    __shared__ float xs[GN * IN_CH];
    int f32 = *flag;
    int tid = threadIdx.x;
    int nl = tid >> 7, c = tid & 127;
    int node0 = blockIdx.x * GN;
    for (int idx = tid; idx < GN * IN_CH; idx += 512) {
        int r = idx / IN_CH, k = idx - r * IN_CH;
        int gr = node0 + r; if (gr >= N_NODES) gr = N_NODES - 1;
        xs[idx] = load_f(x, (size_t)gr * IN_CH + k, f32);
    }
    __syncthreads();
    const float* xr = &xs[nl * IN_CH];
    float acc = 0.f;
#pragma unroll 8
    for (int k = 0; k < IN_CH; k++) acc += xr[k] * W[k * OUT_CH + c];
    int n = node0 + nl;
    if (n < N_NODES) h[(size_t)n * OUT_CH + c] = f2bf(acc);
}

// ---------------------------------------------------------------- aggregate + bias + relu + max-pool
__global__ __launch_bounds__(256) void k_agg(const unsigned short* __restrict__ h,
                                             const int* __restrict__ adj,
                                             const int* __restrict__ offs,
                                             const int* __restrict__ deg,
                                             const float* __restrict__ dinv,
                                             const int* __restrict__ batch,
                                             const float* __restrict__ fbc,
                                             unsigned* pooled) {
    int wave = threadIdx.x >> 6, lane = threadIdx.x & 63;
    int node = blockIdx.x * 4 + wave;   // grid = 25000 -> exactly N_NODES
    float dv = dinv[node];

    unsigned hv = *(const unsigned*)(h + (size_t)node * OUT_CH + lane * 2);
    float sw = dv * dv;
    float a0 = __uint_as_float((hv & 0xffffu) << 16) * sw;
    float a1 = __uint_as_float(hv & 0xffff0000u) * sw;

    int o = offs[node], n = deg[node];
    if (o < 0) o = 0;
    if (n < 0) n = 0;
    long long e = (long long)o + n; if (e > 2LL * N_EDGES) e = 2LL * N_EDGES;
    for (long long i = o; i < e; i++) {
        unsigned u = (unsigned)adj[i];
        if (u >= N_NODES) continue;     // guard: poison/garbage index can't fetch OOB
        unsigned p = *(const unsigned*)(h + (size_t)u * OUT_CH + lane * 2);
        float w = dinv[u] * dv;
        a0 += __uint_as_float((p & 0xffffu) << 16) * w;
        a1 += __uint_as_float(p & 0xffff0000u) * w;
    }
    a0 = fmaxf(a0 + fbc[lane * 2], 0.f);
    a1 = fmaxf(a1 + fbc[lane * 2 + 1], 0.f);

    int g = batch[node];
    __shared__ float s0[256], s1[256];
    __shared__ int sg[4];
    s0[threadIdx.x] = a0; s1[threadIdx.x] = a1;
    if (lane == 0) sg[wave] = g;
    __syncthreads();
    if (wave == 0) {
        int g0 = sg[0];
        if (sg[1] == g0 && sg[2] == g0 && sg[3] == g0) {
            float m0 = fmaxf(fmaxf(s0[lane], s0[64 + lane]), fmaxf(s0[128 + lane], s0[192 + lane]));
            float m1 = fmaxf(fmaxf(s1[lane], s1[64 + lane]), fmaxf(s1[128 + lane], s1[192 + lane]));
            atomicMax(&pooled[g0 * OUT_CH + lane * 2],     __float_as_uint(m0));
            atomicMax(&pooled[g0 * OUT_CH + lane * 2 + 1], __float_as_uint(m1));
        } else {
#pragma unroll
            for (int w = 0; w < 4; w++) {
                atomicMax(&pooled[sg[w] * OUT_CH + lane * 2],     __float_as_uint(s0[w * 64 + lane]));
                atomicMax(&pooled[sg[w] * OUT_CH + lane * 2 + 1], __float_as_uint(s1[w * 64 + lane]));
            }
        }
    }
}

// ---------------------------------------------------------------- root (first node per graph)
__global__ void k_root(const int* __restrict__ batch, int* root) {
    int i = blockIdx.x * blockDim.x + threadIdx.x;
    if (i >= N_NODES) return;
    int b = batch[i];
    if (i == 0 || batch[i - 1] != b) root[b] = i;
}

// ---------------------------------------------------------------- news = relu(x[root] @ W0 + b0)
__global__ __launch_bounds__(128) void k_news(const int* __restrict__ flag,
                                              const void* __restrict__ x,
                                              const int* __restrict__ root,
                                              const float* __restrict__ W0,
                                              const float* __restrict__ b0,
                                              float* news) {
    __shared__ float xs[IN_CH];
    int f32 = *flag;
    int g = blockIdx.x, c = threadIdx.x;
    int r = root[g];
    for (int j = c; j < IN_CH; j += 128) xs[j] = load_f(x, (size_t)r * IN_CH + j, f32);
    __syncthreads();
    float acc = 0.f;
#pragma unroll 8
    for (int k = 0; k < IN_CH; k++) acc += xs[k] * W0[k * OUT_CH + c];
    news[g * OUT_CH + c] = fmaxf(acc + b0[c], 0.f);
}

// ---------------------------------------------------------------- head: lin1 + lin2 + log_softmax
__global__ __launch_bounds__(128) void k_final(const int* __restrict__ flag,
                                               const float* __restrict__ news,
                                               const unsigned* __restrict__ pooled,
                                               const float* __restrict__ W1,
                                               const float* __restrict__ b1,
                                               const float* __restrict__ W2,
                                               const float* __restrict__ b2,
                                               void* out) {
    __shared__ float ins[2 * OUT_CH];
    __shared__ float h2s[OUT_CH];
    int g = blockIdx.x, c = threadIdx.x;
    ins[c] = news[g * OUT_CH + c];
    ins[OUT_CH + c] = __uint_as_float(pooled[g * OUT_CH + c]);
    __syncthreads();
    float acc = 0.f;
#pragma unroll 8
    for (int k = 0; k < 2 * OUT_CH; k++) acc += ins[k] * W1[k * OUT_CH + c];
    h2s[c] = fmaxf(acc + b1[c], 0.f);
    __syncthreads();
    if (c == 0) {
        float l0 = b2[0], l1 = b2[1];
        for (int k = 0; k < OUT_CH; k++) { float v = h2s[k]; l0 += v * W2[k * 2]; l1 += v * W2[k * 2 + 1]; }
        float m = fmaxf(l0, l1);
        float ls = m + logf(expf(l0 - m) + expf(l1 - m));
        if (*flag) {
            ((float*)out)[g * 2]     = l0 - ls;
            ((float*)out)[g * 2 + 1] = l1 - ls;
        } else {
            ((unsigned short*)out)[g * 2]     = f2bf(l0 - ls);
            ((unsigned short*)out)[g * 2 + 1] = f2bf(l1 - ls);
        }
    }
}

// ---------------------------------------------------------------- launch
extern "C" void kernel_launch(void* const* d_in, const int* in_sizes, int n_in,
                              void* d_out, int out_size, void* d_ws, size_t ws_size,
                              hipStream_t stream) {
    const void* x     = d_in[0];
    const int*  ei    = (const int*)d_in[1];
    const int*  batch = (const int*)d_in[2];
    const void* Wc    = d_in[4];
    const void* bc    = d_in[5];
    const void* W0    = d_in[6];
    const void* b0    = d_in[7];
    const void* W1    = d_in[8];
    const void* b1    = d_in[9];
    const void* W2    = d_in[10];
    const void* b2    = d_in[11];
    const int* src = ei;
    const int* dst = ei + N_EDGES;

    char* p = (char*)d_ws;
    auto carve = [&](size_t bytes) -> void* {
        void* r = (void*)p;
        p += (bytes + 255) & ~(size_t)255;
        return r;
    };
    int*      flag      = (int*)carve(4);
    int*      deg       = (int*)carve((size_t)N_NODES * 4);
    int*      cursor    = (int*)carve((size_t)N_NODES * 4);
    int*      offs      = (int*)carve((size_t)N_NODES * 4);
    int*      blockSums = (int*)carve(128 * 4);
    int*      blockOffs = (int*)carve(128 * 4);
    float*    dinv      = (float*)carve((size_t)N_NODES * 4);
    int*      root      = (int*)carve(128 * 4);
    unsigned* pooled    = (unsigned*)carve((size_t)N_GRAPHS * OUT_CH * 4);
    float*    news      = (float*)carve((size_t)N_GRAPHS * OUT_CH * 4);
    float*    fWc       = (float*)carve((size_t)IN_CH * OUT_CH * 4);
    float*    fW0       = (float*)carve((size_t)IN_CH * OUT_CH * 4);
    float*    fW1       = (float*)carve((size_t)2 * OUT_CH * OUT_CH * 4);
    float*    fW2       = (float*)carve((size_t)OUT_CH * 2 * 4);
    float*    fbc       = (float*)carve((size_t)OUT_CH * 4);
    float*    fb0       = (float*)carve((size_t)OUT_CH * 4);
    float*    fb1       = (float*)carve((size_t)OUT_CH * 4);
    float*    fb2       = (float*)carve(2 * 4);
    int*      adj       = (int*)carve((size_t)2 * N_EDGES * 4);
    unsigned short* h   = (unsigned short*)carve((size_t)N_NODES * OUT_CH * 2);

    k_detect<<<1, 256, 0, stream>>>((const unsigned short*)x, flag);
    k_init  <<<391, 256, 0, stream>>>(flag, deg, pooled, root, Wc, bc, W0, b0, W1, b1, W2, b2,
                                      fWc, fbc, fW0, fb0, fW1, fb1, fW2, fb2);
    k_count <<<6250, 256, 0, stream>>>(src, dst, deg);
    k_dinv  <<<391, 256, 0, stream>>>(deg, dinv);
    k_scan1 <<<98, 256, 0, stream>>>(deg, offs, blockSums);
    k_scan2 <<<1, 64, 0, stream>>>(blockSums, blockOffs, 98);
    k_scan3 <<<391, 256, 0, stream>>>(offs, blockOffs, cursor);
    k_fill  <<<6250, 256, 0, stream>>>(src, dst, cursor, adj);
    k_gemm  <<<N_NODES / GN, 512, 0, stream>>>(flag, x, fWc, h);
    k_agg   <<<N_NODES / 4, 256, 0, stream>>>(h, adj, offs, deg, dinv, batch, fbc, pooled);
    k_root  <<<391, 256, 0, stream>>>(batch, root);
    k_news  <<<N_GRAPHS, 128, 0, stream>>>(flag, x, root, fW0, fb0, news);
    k_final <<<N_GRAPHS, 128, 0, stream>>>(flag, news, pooled, fW1, fb1, fW2, fb2, d_out);
}

// Round 3
// 1198.034 us; speedup vs baseline: 1.9739x; 1.9739x over previous
//
#include <hip/hip_runtime.h>

#define N_NODES 100000
#define N_EDGES 1600000
#define N_GRAPHS 128
#define IN_CH 768
#define OUT_CH 128

using short8 = __attribute__((ext_vector_type(8))) short;
using f32x4  = __attribute__((ext_vector_type(4))) float;

__device__ __forceinline__ float bf2f(unsigned short u) {
    return __uint_as_float(((unsigned)u) << 16);
}
__device__ __forceinline__ unsigned short f2bf(float f) {
    unsigned u = __float_as_uint(f);
    u += 0x7fffu + ((u >> 16) & 1u);   // round-to-nearest-even
    return (unsigned short)(u >> 16);
}
__device__ __forceinline__ float load_f(const void* p, size_t i, int f32) {
    return f32 ? ((const float*)p)[i] : bf2f(((const unsigned short*)p)[i]);
}
__device__ __forceinline__ float lo16(unsigned p) { return __uint_as_float((p & 0xffffu) << 16); }
__device__ __forceinline__ float hi16(unsigned p) { return __uint_as_float(p & 0xffff0000u); }

// ---------------------------------------------------------------- dtype detect
__global__ void k_detect(const unsigned short* __restrict__ x, int* flag) {
    __shared__ int s;
    if (threadIdx.x == 0) s = 0;
    __syncthreads();
    int bad = 0;
    for (int j = threadIdx.x; j < 8192; j += 256) {
        float v = bf2f(x[j]);
        if (!(v > -64.f && v < 64.f)) bad = 1;
    }
    if (bad) atomicOr(&s, 1);
    __syncthreads();
    if (threadIdx.x == 0) *flag = s;
}

// ---------------------------------------------------------------- init + weight canonicalization
__global__ void k_init(const int* __restrict__ flag, int* deg, unsigned* pooled, int* root,
                       const void* Wc, const void* bc, const void* W0, const void* b0,
                       const void* W1, const void* b1, const void* W2, const void* b2,
                       unsigned short* Wt, float* fbc, float* fW0, float* fb0,
                       float* fW1, float* fb1, float* fW2, float* fb2) {
    int f32 = *flag;
    int i = blockIdx.x * blockDim.x + threadIdx.x;
    if (i < N_NODES) deg[i] = 0;
    if (i < N_GRAPHS * OUT_CH) pooled[i] = 0u;
    if (i < N_GRAPHS) root[i] = 0;
    if (i < IN_CH * OUT_CH) {
        int n = i / IN_CH, k = i - n * IN_CH;     // Wt[n][k] = W_conv[k][n], bf16
        Wt[i] = f32 ? f2bf(((const float*)Wc)[k * OUT_CH + n])
                    : ((const unsigned short*)Wc)[k * OUT_CH + n];
        fW0[i] = load_f(W0, i, f32);
    }
    if (i < 2 * OUT_CH * OUT_CH) fW1[i] = load_f(W1, i, f32);
    if (i < OUT_CH * 2) fW2[i] = load_f(W2, i, f32);
    if (i < OUT_CH) { fbc[i] = load_f(bc, i, f32); fb0[i] = load_f(b0, i, f32); fb1[i] = load_f(b1, i, f32); }
    if (i < 2) fb2[i] = load_f(b2, i, f32);
}

// ---------------------------------------------------------------- degree count
__global__ void k_count(const int* __restrict__ src, const int* __restrict__ dst, int* deg) {
    int i = blockIdx.x * blockDim.x + threadIdx.x;
    if (i >= N_EDGES) return;
    atomicAdd(&deg[src[i]], 1);
    atomicAdd(&deg[dst[i]], 1);
}

__global__ void k_dinv(const int* __restrict__ deg, float* dinv) {
    int i = blockIdx.x * blockDim.x + threadIdx.x;
    if (i >= N_NODES) return;
    int d = deg[i]; if (d < 0) d = 0;
    dinv[i] = rsqrtf((float)(d + 1));           // +1 self-loop
}

// ---------------------------------------------------------------- exclusive scan (3 stages)
__global__ void k_scan1(const int* __restrict__ deg, int* offs, int* blockSums) {
    __shared__ int s[256];
    int tid = threadIdx.x;
    int base = blockIdx.x * 1024 + tid * 4;
    int v[4]; int t = 0;
#pragma unroll
    for (int j = 0; j < 4; j++) {
        int idx = base + j;
        v[j] = (idx < N_NODES) ? deg[idx] : 0;
        t += v[j];
    }
    s[tid] = t;
    __syncthreads();
    for (int off = 1; off < 256; off <<= 1) {
        int add = (tid >= off) ? s[tid - off] : 0;
        __syncthreads();
        s[tid] += add;
        __syncthreads();
    }
    int excl = s[tid] - t;
#pragma unroll
    for (int j = 0; j < 4; j++) {
        int idx = base + j;
        if (idx < N_NODES) offs[idx] = excl;
        excl += v[j];
    }
    if (tid == 255) blockSums[blockIdx.x] = s[255];
}

__global__ void k_scan2(const int* __restrict__ blockSums, int* blockOffs, int nb) {
    if (threadIdx.x == 0 && blockIdx.x == 0) {
        int acc = 0;
        for (int b = 0; b < nb; b++) { int t = blockSums[b]; blockOffs[b] = acc; acc += t; }
    }
}

__global__ void k_scan3(int* offs, const int* __restrict__ blockOffs, int* cursor) {
    int i = blockIdx.x * blockDim.x + threadIdx.x;
    if (i >= N_NODES) return;
    int o = offs[i] + blockOffs[i >> 10];
    offs[i] = o;
    cursor[i] = o;
}

// ---------------------------------------------------------------- CSR fill
__global__ void k_fill(const int* __restrict__ src, const int* __restrict__ dst,
                       int* cursor, int* adj) {
    int i = blockIdx.x * blockDim.x + threadIdx.x;
    if (i >= N_EDGES) return;
    int s = src[i], d = dst[i];
    adj[atomicAdd(&cursor[d], 1)] = s;
    adj[atomicAdd(&cursor[s], 1)] = d;
}

// ---------------------------------------------------------------- GEMM h = x @ W_conv (bf16 MFMA, 128x128 tile)
#define MBLK 128
#define BK 64
#define LSTR 72   // padded LDS row stride in shorts (144 B, 16-aligned)

__global__ __launch_bounds__(256) void k_gemm(const int* __restrict__ flag,
                                              const void* __restrict__ xv,
                                              const unsigned short* __restrict__ Wt,
                                              unsigned short* __restrict__ h) {
    __shared__ __align__(16) unsigned short As[MBLK * LSTR];
    __shared__ __align__(16) unsigned short Bs[OUT_CH * LSTR];
    const int f32 = *flag;
    const int tid = threadIdx.x;
    const int wave = tid >> 6, lane = tid & 63;
    const int quad = lane >> 4, l16 = lane & 15;
    const int wm = (wave >> 1) * 64, wn = (wave & 1) * 64;
    const int row0 = blockIdx.x * MBLK;

    f32x4 acc[4][4];
#pragma unroll
    for (int mt = 0; mt < 4; mt++)
#pragma unroll
        for (int nt = 0; nt < 4; nt++) acc[mt][nt] = (f32x4){0.f, 0.f, 0.f, 0.f};

    for (int k0 = 0; k0 < IN_CH; k0 += BK) {
        // stage A (128x64) and B (128x64): 1024 16-byte chunks each, 4 per thread
#pragma unroll
        for (int i = 0; i < 4; i++) {
            int chunk = tid + i * 256;            // 0..1023
            int r = chunk >> 3, c8 = (chunk & 7) << 3;
            int gr = row0 + r; if (gr >= N_NODES) gr = N_NODES - 1;
            uint4 va;
            if (f32) {
                const float* xp = (const float*)xv + (size_t)gr * IN_CH + k0 + c8;
                unsigned short t[8];
#pragma unroll
                for (int j = 0; j < 8; j++) t[j] = f2bf(xp[j]);
                va = *(const uint4*)t;
            } else {
                va = *(const uint4*)((const unsigned short*)xv + (size_t)gr * IN_CH + k0 + c8);
            }
            *(uint4*)&As[r * LSTR + c8] = va;
            uint4 vb = *(const uint4*)(Wt + (size_t)r * IN_CH + k0 + c8);
            *(uint4*)&Bs[r * LSTR + c8] = vb;
        }
        __syncthreads();
#pragma unroll
        for (int kk = 0; kk < BK; kk += 32) {
            short8 af[4], bf[4];
#pragma unroll
            for (int mt = 0; mt < 4; mt++)
                af[mt] = *(const short8*)&As[(wm + mt * 16 + l16) * LSTR + kk + quad * 8];
#pragma unroll
            for (int nt = 0; nt < 4; nt++)
                bf[nt] = *(const short8*)&Bs[(wn + nt * 16 + l16) * LSTR + kk + quad * 8];
#pragma unroll
            for (int mt = 0; mt < 4; mt++)
#pragma unroll
                for (int nt = 0; nt < 4; nt++)
                    acc[mt][nt] = __builtin_amdgcn_mfma_f32_16x16x32_bf16(af[mt], bf[nt], acc[mt][nt], 0, 0, 0);
        }
        __syncthreads();
    }

#pragma unroll
    for (int mt = 0; mt < 4; mt++) {
#pragma unroll
        for (int nt = 0; nt < 4; nt++) {
            int col = wn + nt * 16 + l16;
#pragma unroll
            for (int r = 0; r < 4; r++) {
                int m = row0 + wm + mt * 16 + quad * 4 + r;
                if (m < N_NODES) h[(size_t)m * OUT_CH + col] = f2bf(acc[mt][nt][r]);
            }
        }
    }
}

// ---------------------------------------------------------------- aggregate + bias + relu + max-pool
__global__ __launch_bounds__(256) void k_agg(const unsigned short* __restrict__ h,
                                             const int* __restrict__ adj,
                                             const int* __restrict__ offs,
                                             const int* __restrict__ deg,
                                             const float* __restrict__ dinv,
                                             const int* __restrict__ batch,
                                             const float* __restrict__ fbc,
                                             unsigned* pooled) {
    int wave = threadIdx.x >> 6, lane = threadIdx.x & 63;
    int node = blockIdx.x * 4 + wave;   // grid = 25000 -> exactly N_NODES
    float dv = dinv[node];

    unsigned hv = *(const unsigned*)(h + (size_t)node * OUT_CH + lane * 2);
    float sw = dv * dv;
    float a0 = lo16(hv) * sw;
    float a1 = hi16(hv) * sw;

    int o = offs[node], n = deg[node];
    if (o < 0) o = 0;
    if (n < 0) n = 0;
    int e = o + n; if (e > 2 * N_EDGES) e = 2 * N_EDGES;
    int i = o;
    for (; i + 4 <= e; i += 4) {
        unsigned u0 = (unsigned)adj[i], u1 = (unsigned)adj[i + 1];
        unsigned u2 = (unsigned)adj[i + 2], u3 = (unsigned)adj[i + 3];
        unsigned c0 = u0 < N_NODES ? u0 : N_NODES - 1u;
        unsigned c1 = u1 < N_NODES ? u1 : N_NODES - 1u;
        unsigned c2 = u2 < N_NODES ? u2 : N_NODES - 1u;
        unsigned c3 = u3 < N_NODES ? u3 : N_NODES - 1u;
        unsigned p0 = *(const unsigned*)(h + (size_t)c0 * OUT_CH + lane * 2);
        unsigned p1 = *(const unsigned*)(h + (size_t)c1 * OUT_CH + lane * 2);
        unsigned p2 = *(const unsigned*)(h + (size_t)c2 * OUT_CH + lane * 2);
        unsigned p3 = *(const unsigned*)(h + (size_t)c3 * OUT_CH + lane * 2);
        float w0 = (u0 < N_NODES) ? dinv[c0] * dv : 0.f;
        float w1 = (u1 < N_NODES) ? dinv[c1] * dv : 0.f;
        float w2 = (u2 < N_NODES) ? dinv[c2] * dv : 0.f;
        float w3 = (u3 < N_NODES) ? dinv[c3] * dv : 0.f;
        a0 += lo16(p0) * w0 + lo16(p1) * w1 + lo16(p2) * w2 + lo16(p3) * w3;
        a1 += hi16(p0) * w0 + hi16(p1) * w1 + hi16(p2) * w2 + hi16(p3) * w3;
    }
    for (; i < e; i++) {
        unsigned u = (unsigned)adj[i];
        unsigned c = u < N_NODES ? u : N_NODES - 1u;
        unsigned p = *(const unsigned*)(h + (size_t)c * OUT_CH + lane * 2);
        float w = (u < N_NODES) ? dinv[c] * dv : 0.f;
        a0 += lo16(p) * w;
        a1 += hi16(p) * w;
    }
    a0 = fmaxf(a0 + fbc[lane * 2], 0.f);
    a1 = fmaxf(a1 + fbc[lane * 2 + 1], 0.f);

    int g = batch[node];
    __shared__ float s0[256], s1[256];
    __shared__ int sg[4];
    s0[threadIdx.x] = a0; s1[threadIdx.x] = a1;
    if (lane == 0) sg[wave] = g;
    __syncthreads();
    if (wave == 0) {
        int g0 = sg[0];
        if (sg[1] == g0 && sg[2] == g0 && sg[3] == g0) {
            float m0 = fmaxf(fmaxf(s0[lane], s0[64 + lane]), fmaxf(s0[128 + lane], s0[192 + lane]));
            float m1 = fmaxf(fmaxf(s1[lane], s1[64 + lane]), fmaxf(s1[128 + lane], s1[192 + lane]));
            atomicMax(&pooled[g0 * OUT_CH + lane * 2],     __float_as_uint(m0));
            atomicMax(&pooled[g0 * OUT_CH + lane * 2 + 1], __float_as_uint(m1));
        } else {
#pragma unroll
            for (int w = 0; w < 4; w++) {
                atomicMax(&pooled[sg[w] * OUT_CH + lane * 2],     __float_as_uint(s0[w * 64 + lane]));
                atomicMax(&pooled[sg[w] * OUT_CH + lane * 2 + 1], __float_as_uint(s1[w * 64 + lane]));
            }
        }
    }
}

// ---------------------------------------------------------------- root (first node per graph)
__global__ void k_root(const int* __restrict__ batch, int* root) {
    int i = blockIdx.x * blockDim.x + threadIdx.x;
    if (i >= N_NODES) return;
    int b = batch[i];
    if (i == 0 || batch[i - 1] != b) root[b] = i;
}

// ---------------------------------------------------------------- news = relu(x[root] @ W0 + b0)
__global__ __launch_bounds__(128) void k_news(const int* __restrict__ flag,
                                              const void* __restrict__ x,
                                              const int* __restrict__ root,
                                              const float* __restrict__ W0,
                                              const float* __restrict__ b0,
                                              float* news) {
    __shared__ float xs[IN_CH];
    int f32 = *flag;
    int g = blockIdx.x, c = threadIdx.x;
    int r = root[g];
    for (int j = c; j < IN_CH; j += 128) xs[j] = load_f(x, (size_t)r * IN_CH + j, f32);
    __syncthreads();
    float acc = 0.f;
#pragma unroll 8
    for (int k = 0; k < IN_CH; k++) acc += xs[k] * W0[k * OUT_CH + c];
    news[g * OUT_CH + c] = fmaxf(acc + b0[c], 0.f);
}

// ---------------------------------------------------------------- head: lin1 + lin2 + log_softmax
__global__ __launch_bounds__(128) void k_final(const int* __restrict__ flag,
                                               const float* __restrict__ news,
                                               const unsigned* __restrict__ pooled,
                                               const float* __restrict__ W1,
                                               const float* __restrict__ b1,
                                               const float* __restrict__ W2,
                                               const float* __restrict__ b2,
                                               void* out) {
    __shared__ float ins[2 * OUT_CH];
    __shared__ float h2s[OUT_CH];
    int g = blockIdx.x, c = threadIdx.x;
    ins[c] = news[g * OUT_CH + c];
    ins[OUT_CH + c] = __uint_as_float(pooled[g * OUT_CH + c]);
    __syncthreads();
    float acc = 0.f;
#pragma unroll 8
    for (int k = 0; k < 2 * OUT_CH; k++) acc += ins[k] * W1[k * OUT_CH + c];
    h2s[c] = fmaxf(acc + b1[c], 0.f);
    __syncthreads();
    if (c == 0) {
        float l0 = b2[0], l1 = b2[1];
        for (int k = 0; k < OUT_CH; k++) { float v = h2s[k]; l0 += v * W2[k * 2]; l1 += v * W2[k * 2 + 1]; }
        float m = fmaxf(l0, l1);
        float ls = m + logf(expf(l0 - m) + expf(l1 - m));
        if (*flag) {
            ((float*)out)[g * 2]     = l0 - ls;
            ((float*)out)[g * 2 + 1] = l1 - ls;
        } else {
            ((unsigned short*)out)[g * 2]     = f2bf(l0 - ls);
            ((unsigned short*)out)[g * 2 + 1] = f2bf(l1 - ls);
        }
    }
}

// ---------------------------------------------------------------- launch
extern "C" void kernel_launch(void* const* d_in, const int* in_sizes, int n_in,
                              void* d_out, int out_size, void* d_ws, size_t ws_size,
                              hipStream_t stream) {
    const void* x     = d_in[0];
    const int*  ei    = (const int*)d_in[1];
    const int*  batch = (const int*)d_in[2];
    const void* Wc    = d_in[4];
    const void* bc    = d_in[5];
    const void* W0    = d_in[6];
    const void* b0    = d_in[7];
    const void* W1    = d_in[8];
    const void* b1    = d_in[9];
    const void* W2    = d_in[10];
    const void* b2    = d_in[11];
    const int* src = ei;
    const int* dst = ei + N_EDGES;

    char* p = (char*)d_ws;
    auto carve = [&](size_t bytes) -> void* {
        void* r = (void*)p;
        p += (bytes + 255) & ~(size_t)255;
        return r;
    };
    int*      flag      = (int*)carve(4);
    int*      deg       = (int*)carve((size_t)N_NODES * 4);
    int*      cursor    = (int*)carve((size_t)N_NODES * 4);
    int*      offs      = (int*)carve((size_t)N_NODES * 4);
    int*      blockSums = (int*)carve(128 * 4);
    int*      blockOffs = (int*)carve(128 * 4);
    float*    dinv      = (float*)carve((size_t)N_NODES * 4);
    int*      root      = (int*)carve(128 * 4);
    unsigned* pooled    = (unsigned*)carve((size_t)N_GRAPHS * OUT_CH * 4);
    float*    news      = (float*)carve((size_t)N_GRAPHS * OUT_CH * 4);
    unsigned short* Wt  = (unsigned short*)carve((size_t)IN_CH * OUT_CH * 2);
    float*    fW0       = (float*)carve((size_t)IN_CH * OUT_CH * 4);
    float*    fW1       = (float*)carve((size_t)2 * OUT_CH * OUT_CH * 4);
    float*    fW2       = (float*)carve((size_t)OUT_CH * 2 * 4);
    float*    fbc       = (float*)carve((size_t)OUT_CH * 4);
    float*    fb0       = (float*)carve((size_t)OUT_CH * 4);
    float*    fb1       = (float*)carve((size_t)OUT_CH * 4);
    float*    fb2       = (float*)carve(2 * 4);
    int*      adj       = (int*)carve((size_t)2 * N_EDGES * 4);
    unsigned short* h   = (unsigned short*)carve((size_t)N_NODES * OUT_CH * 2);

    k_detect<<<1, 256, 0, stream>>>((const unsigned short*)x, flag);
    k_init  <<<391, 256, 0, stream>>>(flag, deg, pooled, root, Wc, bc, W0, b0, W1, b1, W2, b2,
                                      Wt, fbc, fW0, fb0, fW1, fb1, fW2, fb2);
    k_count <<<6250, 256, 0, stream>>>(src, dst, deg);
    k_dinv  <<<391, 256, 0, stream>>>(deg, dinv);
    k_scan1 <<<98, 256, 0, stream>>>(deg, offs, blockSums);
    k_scan2 <<<1, 64, 0, stream>>>(blockSums, blockOffs, 98);
    k_scan3 <<<391, 256, 0, stream>>>(offs, blockOffs, cursor);
    k_fill  <<<6250, 256, 0, stream>>>(src, dst, cursor, adj);
    k_gemm  <<<(N_NODES + MBLK - 1) / MBLK, 256, 0, stream>>>(flag, x, Wt, h);
    k_agg   <<<N_NODES / 4, 256, 0, stream>>>(h, adj, offs, deg, dinv, batch, fbc, pooled);
    k_root  <<<391, 256, 0, stream>>>(batch, root);
    k_news  <<<N_GRAPHS, 128, 0, stream>>>(flag, x, root, fW0, fb0, news);
    k_final <<<N_GRAPHS, 128, 0, stream>>>(flag, news, pooled, fW1, fb1, fW2, fb2, d_out);
}